// Round 8
// baseline (159.882 us; speedup 1.0000x reference)
//
#include <hip/hip_runtime.h>
#include <math.h>

#define L_DIM   8192
#define NCH     64
#define M_TOT_F 262144.0f
#define EPS_F   1e-5f
#define GBLK    512
#define GTPB    8     // gram tiles per block: 512*8 = 4096
#define ATPB    4     // apply tiles per block: 1024*4 = 4096

typedef float f32x4 __attribute__((ext_vector_type(4)));
typedef short bf16x8 __attribute__((ext_vector_type(8)));

union U8 { unsigned u[4]; bf16x8 v; };

// split two fp32 into packed bf16 hi (truncated) and bf16 lo (residual)
__device__ __forceinline__ void cvt2(float f0, float f1, unsigned& h, unsigned& l) {
    unsigned u0 = __float_as_uint(f0), u1 = __float_as_uint(f1);
    h = (u0 >> 16) | (u1 & 0xFFFF0000u);
    float r0 = f0 - __uint_as_float(u0 & 0xFFFF0000u);
    float r1 = f1 - __uint_as_float(u1 & 0xFFFF0000u);
    l = (__float_as_uint(r0) >> 16) | (__float_as_uint(r1) & 0xFFFF0000u);
}

__device__ __forceinline__ void split16(float v, unsigned short& h, unsigned short& l) {
    unsigned u = __float_as_uint(v);
    h = (unsigned short)(u >> 16);
    float r = v - __uint_as_float(u & 0xFFFF0000u);
    l = (unsigned short)(__float_as_uint(r) >> 16);
}

__device__ __forceinline__ f32x4 mfma16(bf16x8 a, bf16x8 b, f32x4 c) {
    return __builtin_amdgcn_mfma_f32_16x16x32_bf16(a, b, c, 0, 0, 0);
}

__device__ __forceinline__ f32x4 fzero() {
    f32x4 z; z[0] = 0.f; z[1] = 0.f; z[2] = 0.f; z[3] = 0.f; return z;
}

// ---------------- K1: Gram — depth-4 register pipeline, atomicAdd epilogue ----------
__global__ __launch_bounds__(256) void gram_kernel(const float* __restrict__ X,
                                                   float* __restrict__ ws) {
    __shared__ __align__(16) unsigned short hfrag[2][4096];
    __shared__ __align__(16) unsigned short lfrag[2][4096];
    const int tid  = threadIdx.x;
    const int w    = tid >> 6;
    const int lane = tid & 63;
    const int m    = lane & 15;
    const int q    = lane >> 4;
    const int row  = 16 * w + m;

    f32x4 acc1[4], acc2[4];
#pragma unroll
    for (int nb = 0; nb < 4; ++nb) { acc1[nb] = fzero(); acc2[nb] = fzero(); }
    float sacc = 0.f;

    const int tile0 = blockIdx.x * GTPB;
    float4 v[4][4];   // 4-deep pipeline: 16 float4 in flight

#define LDT(slot, tt)  {                                                                   \
        const float* src_ = X + ((size_t)(((tt) >> 7) * NCH + row)) * L_DIM                \
                              + (((tt) & 127) << 6) + 8 * q;                               \
        v[slot][0] = *(const float4*)(src_);                                               \
        v[slot][1] = *(const float4*)(src_ + 4);                                           \
        v[slot][2] = *(const float4*)(src_ + 32);                                          \
        v[slot][3] = *(const float4*)(src_ + 36);                                          \
    }

#pragma unroll
    for (int t = 0; t < 4; ++t) LDT(t, tile0 + t)

#pragma unroll
    for (int t = 0; t < GTPB; ++t) {
        const int slot = t & 3;
        const int p    = t & 1;
#pragma unroll
        for (int i = 0; i < 4; ++i)
            sacc += v[slot][i].x + v[slot][i].y + v[slot][i].z + v[slot][i].w;

        bf16x8 Ah[2], Al[2];
#pragma unroll
        for (int k = 0; k < 2; ++k) {
            U8 H, L;
            cvt2(v[slot][2 * k].x,     v[slot][2 * k].y,     H.u[0], L.u[0]);
            cvt2(v[slot][2 * k].z,     v[slot][2 * k].w,     H.u[1], L.u[1]);
            cvt2(v[slot][2 * k + 1].x, v[slot][2 * k + 1].y, H.u[2], L.u[2]);
            cvt2(v[slot][2 * k + 1].z, v[slot][2 * k + 1].w, H.u[3], L.u[3]);
            Ah[k] = H.v; Al[k] = L.v;
            int chunk = ((w * 2 + k) * 4 + q) * 16 + m;
            *(bf16x8*)&hfrag[p][chunk * 8] = H.v;
            *(bf16x8*)&lfrag[p][chunk * 8] = L.v;
        }

        if (t + 4 < GTPB) LDT(slot, tile0 + t + 4)   // refill freed slot, 4 ahead
        __syncthreads();

#pragma unroll
        for (int k = 0; k < 2; ++k)
#pragma unroll
            for (int nb = 0; nb < 4; ++nb) {
                int chunk = ((nb * 2 + k) * 4 + q) * 16 + m;
                bf16x8 bh = *(const bf16x8*)&hfrag[p][chunk * 8];
                bf16x8 bl = *(const bf16x8*)&lfrag[p][chunk * 8];
                acc1[nb] = mfma16(Ah[k], bh, acc1[nb]);
                acc2[nb] = mfma16(Ah[k], bl, acc2[nb]);
            }
    }
#undef LDT

    // device-scope atomic accumulation (R4-proven: coherent, absmax unchanged)
#pragma unroll
    for (int nb = 0; nb < 4; ++nb)
#pragma unroll
        for (int r = 0; r < 4; ++r) {
            int grow = 16 * w + 4 * q + r;
            int gcol = 16 * nb + m;
            atomicAdd(&ws[grow * 64 + gcol],        acc1[nb][r]);
            atomicAdd(&ws[4096 + grow * 64 + gcol], acc2[nb][r]);
        }
    sacc += __shfl_xor(sacc, 16);
    sacc += __shfl_xor(sacc, 32);
    if (q == 0) atomicAdd(&ws[8192 + row], sacc);
}

// ---------------- K2: Newton-Schulz — 512 threads, 8-wave split per matmul -----------
// wave w8: rows 16*(w8>>1)..+15, column blocks nb in {2*(w8&1), 2*(w8&1)+1}
__device__ __forceinline__ void mm_core8(f32x4* acc,
                                         const unsigned short* Xh, const unsigned short* Xl,
                                         const unsigned short* Yh, const unsigned short* Yl,
                                         int rg, int nbb, int m, int q) {
#pragma unroll
    for (int k0 = 0; k0 < 64; k0 += 32) {
        bf16x8 xh = *(const bf16x8*)&Xh[(16 * rg + m) * 72 + k0 + 8 * q];
        bf16x8 xl = *(const bf16x8*)&Xl[(16 * rg + m) * 72 + k0 + 8 * q];
#pragma unroll
        for (int j = 0; j < 2; ++j) {
            int nb = nbb + j;
            bf16x8 yh = *(const bf16x8*)&Yh[(16 * nb + m) * 72 + k0 + 8 * q];
            bf16x8 yl = *(const bf16x8*)&Yl[(16 * nb + m) * 72 + k0 + 8 * q];
            acc[j] = mfma16(xh, yh, acc[j]);
            acc[j] = mfma16(xh, yl, acc[j]);
            acc[j] = mfma16(xl, yh, acc[j]);
        }
    }
}

__device__ __forceinline__ void mm_pl8(unsigned short* Dh, unsigned short* Dl,
                                       const unsigned short* Xh, const unsigned short* Xl,
                                       const unsigned short* Yh, const unsigned short* Yl,
                                       int rg, int nbb, int m, int q) {
    f32x4 acc[2];
    acc[0] = fzero(); acc[1] = fzero();
    mm_core8(acc, Xh, Xl, Yh, Yl, rg, nbb, m, q);
#pragma unroll
    for (int j = 0; j < 2; ++j)
#pragma unroll
        for (int r = 0; r < 4; ++r) {
            int row = 16 * rg + 4 * q + r, col = 16 * (nbb + j) + m;
            unsigned short h, l;
            split16(acc[j][r], h, l);
            Dh[row * 72 + col] = h;
            Dl[row * 72 + col] = l;
        }
}

__global__ __launch_bounds__(512) void ns_kernel(float* __restrict__ ws) {
    __shared__ __align__(16) float Pf[64 * 68];
    __shared__ __align__(16) unsigned short Ph[64 * 72], Pl[64 * 72];
    __shared__ __align__(16) unsigned short Sh[64 * 72], Sl[64 * 72];
    __shared__ __align__(16) unsigned short T1h[64 * 72], T1l[64 * 72];
    __shared__ __align__(16) unsigned short T2h[64 * 72], T2l[64 * 72];
    __shared__ float mu[64];
    __shared__ float scal[2];

    const int tid = threadIdx.x;
    const int w8 = tid >> 6, lane = tid & 63;
    const int m = lane & 15, q = lane >> 4;
    const int rg = w8 >> 1, nbb = (w8 & 1) << 1;
    const float inv_m = 1.0f / M_TOT_F;

    if (tid < 64) mu[tid] = ws[8192 + tid] * inv_m;
    __syncthreads();

    if (tid < 64) {
        int e = tid * 65;   // diagonal of the 64x64 planes
        float g  = (ws[e] + 2.0f * ws[4096 + e]) * inv_m;
        float sd = g - mu[tid] * mu[tid] + EPS_F;
#pragma unroll
        for (int off = 32; off >= 1; off >>= 1) sd += __shfl_xor(sd, off);
        if (tid == 0) { scal[0] = 1.0f / sd; scal[1] = sqrtf(1.0f / sd); }
    }
    __syncthreads();
    const float rTr = scal[0];

    // S_N planes + closed-form NS iter 1: P1 = 1.5 I - 0.5 S_N
    for (int e = tid; e < 4096; e += 512) {
        int i = e >> 6, j = e & 63;
        float g   = (ws[e] + ws[4096 + e] + ws[4096 + (j << 6) + i]) * inv_m;
        float sig = g - mu[i] * mu[j] + ((i == j) ? EPS_F : 0.f);
        float sn  = sig * rTr;
        unsigned short h, l;
        split16(sn, h, l);
        Sh[i * 72 + j] = h; Sl[i * 72 + j] = l;
        float pv = ((i == j) ? 1.5f : 0.f) - 0.5f * sn;
        Pf[i * 68 + j] = pv;
        split16(pv, h, l);
        Ph[i * 72 + j] = h; Pl[i * 72 + j] = l;
    }
    __syncthreads();

    for (int it = 0; it < 4; ++it) {
        mm_pl8(T1h, T1l, Ph, Pl, Ph, Pl, rg, nbb, m, q);   // T1 = P^2
        __syncthreads();
        mm_pl8(T2h, T2l, T1h, T1l, Ph, Pl, rg, nbb, m, q); // T2 = P^3
        __syncthreads();
        f32x4 acc[2];                                       // U = P^3 * S_N
        acc[0] = fzero(); acc[1] = fzero();
        mm_core8(acc, T2h, T2l, Sh, Sl, rg, nbb, m, q);
#pragma unroll
        for (int j = 0; j < 2; ++j)
#pragma unroll
            for (int r = 0; r < 4; ++r) {
                int row = 16 * rg + 4 * q + r, col = 16 * (nbb + j) + m;
                int idx = row * 68 + col;
                float pv = 1.5f * Pf[idx] - 0.5f * acc[j][r];
                Pf[idx] = pv;
                unsigned short h, l;
                split16(pv, h, l);
                Ph[row * 72 + col] = h;
                Pl[row * 72 + col] = l;
            }
        __syncthreads();
    }

    const float s = scal[1];
    unsigned short* hp = (unsigned short*)ws;
    unsigned short* lp = hp + 4096;
    for (int e = tid; e < 4096; e += 512) {
        int i = e >> 6, j = e & 63;
        float v = Pf[i * 68 + j] * s;
        unsigned short h, l;
        split16(v, h, l);
        hp[e] = h;
        lp[e] = l;
    }
    if (tid < 64) {
        float a = 0.f;
#pragma unroll 8
        for (int k = 0; k < 64; ++k) a += Pf[tid * 68 + k] * mu[k];
        ws[8256 + tid] = -a * s;
    }
}

// ---------------- K3: Y = wm @ x + bias — all 4 tiles' loads issued upfront ----------
__global__ __launch_bounds__(256) void apply_kernel(const float* __restrict__ X,
                                                    float* __restrict__ Y,
                                                    const float* __restrict__ ws) {
    __shared__ __align__(16) unsigned short hplane[2][4096];
    __shared__ __align__(16) unsigned short lplane[2][4096];
    const int tid  = threadIdx.x;
    const int w    = tid >> 6;
    const int lane = tid & 63;
    const int m    = lane & 15;
    const int q    = lane >> 4;
    const int cp   = tid & 31;      // channel pair rows 2cp, 2cp+1
    const int lg   = tid >> 5;      // 0..7

    const unsigned short* hp = (const unsigned short*)ws;
    const unsigned short* lp = hp + 4096;
    bf16x8 Ah[2], Al[2];
#pragma unroll
    for (int kk = 0; kk < 2; ++kk) {
        Ah[kk] = *(const bf16x8*)&hp[(16 * w + m) * 64 + 32 * kk + 8 * q];
        Al[kk] = *(const bf16x8*)&lp[(16 * w + m) * 64 + 32 * kk + 8 * q];
    }
    const float4 bias4 = *(const float4*)&ws[8256 + 16 * w + 4 * q];

    float4 va[ATPB][2], vb[ATPB][2];   // all tiles in flight: 16 float4 loads
#pragma unroll
    for (int t = 0; t < ATPB; ++t) {
        int tile = blockIdx.x * ATPB + t;
        const float* xb = X + (size_t)(tile >> 7) * (NCH * L_DIM) + ((tile & 127) << 6)
                          + (size_t)(2 * cp) * L_DIM + 4 * lg;
#pragma unroll
        for (int ss = 0; ss < 2; ++ss) {
            va[t][ss] = *(const float4*)(xb + 32 * ss);
            vb[t][ss] = *(const float4*)(xb + 32 * ss + L_DIM);
        }
    }

#pragma unroll
    for (int t = 0; t < ATPB; ++t) {
        int tile = blockIdx.x * ATPB + t;
        int bidx = tile >> 7;
        int l0   = (tile & 127) << 6;
        const int p = t & 1;
        unsigned* hw2 = (unsigned*)hplane[p];
        unsigned* lw2 = (unsigned*)lplane[p];

#pragma unroll
        for (int ss = 0; ss < 2; ++ss) {
            float fa[4], fb[4];
            *(float4*)fa = va[t][ss];
            *(float4*)fb = vb[t][ss];
#pragma unroll
            for (int i = 0; i < 4; ++i) {
                int l = 4 * lg + 32 * ss + i;
                unsigned h, lo2;
                cvt2(fa[i], fb[i], h, lo2);
                int widx = l * 32 + (((cp >> 2) ^ (l & 7)) << 2) + (cp & 3);
                hw2[widx] = h;
                lw2[widx] = lo2;
            }
        }
        __syncthreads();

        f32x4 acc[4];
#pragma unroll
        for (int nb = 0; nb < 4; ++nb) {
            acc[nb][0] = bias4.x; acc[nb][1] = bias4.y;
            acc[nb][2] = bias4.z; acc[nb][3] = bias4.w;
        }
#pragma unroll
        for (int kk = 0; kk < 2; ++kk)
#pragma unroll
            for (int nb = 0; nb < 4; ++nb) {
                int l = 16 * nb + m;
                int saddr = l * 64 + ((((4 * kk + q) ^ (l & 7))) << 3);
                bf16x8 bh = *(const bf16x8*)&hplane[p][saddr];
                bf16x8 bl = *(const bf16x8*)&lplane[p][saddr];
                acc[nb] = mfma16(Ah[kk], bh, acc[nb]);
                acc[nb] = mfma16(Ah[kk], bl, acc[nb]);
                acc[nb] = mfma16(Al[kk], bh, acc[nb]);
            }

#pragma unroll
        for (int nb = 0; nb < 4; ++nb)
#pragma unroll
            for (int rr = 0; rr < 4; ++rr)
                Y[((size_t)bidx * NCH + 16 * w + 4 * q + rr) * L_DIM + l0 + 16 * nb + m] = acc[nb][rr];
    }
}

extern "C" void kernel_launch(void* const* d_in, const int* in_sizes, int n_in,
                              void* d_out, int out_size, void* d_ws, size_t ws_size,
                              hipStream_t stream) {
    const float* X = (const float*)d_in[0];
    float* Y  = (float*)d_out;
    float* ws = (float*)d_ws;

    hipMemsetAsync(ws, 0, 8256 * sizeof(float), stream);
    hipLaunchKernelGGL(gram_kernel,  dim3(GBLK), dim3(256), 0, stream, X, ws);
    hipLaunchKernelGGL(ns_kernel,    dim3(1),    dim3(512), 0, stream, ws);
    hipLaunchKernelGGL(apply_kernel, dim3(1024), dim3(256), 0, stream, X, Y, ws);
}

// Round 10
// 146.989 us; speedup vs baseline: 1.0877x; 1.0877x over previous
//
#include <hip/hip_runtime.h>
#include <math.h>

#define L_DIM   8192
#define NCH     64
#define M_TOT_F 262144.0f
#define EPS_F   1e-5f
#define GTPB    4     // gram tiles per block: 1024*4 = 4096
#define ATPB    4     // apply tiles per block: 1024*4 = 4096
#define PSTRIDE 4224  // symmetric partial stride (4096 matrix + 64 sums + pad)

typedef float f32x4 __attribute__((ext_vector_type(4)));
typedef short bf16x8 __attribute__((ext_vector_type(8)));

union U8 { unsigned u[4]; bf16x8 v; };

// split two fp32 into packed bf16 hi (truncated) and bf16 lo (residual)
__device__ __forceinline__ void cvt2(float f0, float f1, unsigned& h, unsigned& l) {
    unsigned u0 = __float_as_uint(f0), u1 = __float_as_uint(f1);
    h = (u0 >> 16) | (u1 & 0xFFFF0000u);
    float r0 = f0 - __uint_as_float(u0 & 0xFFFF0000u);
    float r1 = f1 - __uint_as_float(u1 & 0xFFFF0000u);
    l = (__float_as_uint(r0) >> 16) | (__float_as_uint(r1) & 0xFFFF0000u);
}

__device__ __forceinline__ void split16(float v, unsigned short& h, unsigned short& l) {
    unsigned u = __float_as_uint(v);
    h = (unsigned short)(u >> 16);
    float r = v - __uint_as_float(u & 0xFFFF0000u);
    l = (unsigned short)(__float_as_uint(r) >> 16);
}

__device__ __forceinline__ f32x4 mfma16(bf16x8 a, bf16x8 b, f32x4 c) {
    return __builtin_amdgcn_mfma_f32_16x16x32_bf16(a, b, c, 0, 0, 0);
}

__device__ __forceinline__ f32x4 fzero() {
    f32x4 z; z[0] = 0.f; z[1] = 0.f; z[2] = 0.f; z[3] = 0.f; return z;
}

// ---------------- K1: Gram — upfront loads, in-block symmetrized partial -------------
// Partial P_b = G1 + G2 + G2^T (symmetric) + 64 row sums: 4160 floats (was 8256).
__global__ __launch_bounds__(256) void gram_kernel(const float* __restrict__ X,
                                                   float* __restrict__ P) {
    __shared__ __align__(16) unsigned char arena[32768];
    unsigned short (*hfrag)[4096] = (unsigned short(*)[4096])(arena);           // [2][4096]
    unsigned short (*lfrag)[4096] = (unsigned short(*)[4096])(arena + 16384);   // [2][4096]
    float* fg2 = (float*)arena;   // 64*65 floats = 16640 B, aliases dbuf (used after loop)

    const int tid  = threadIdx.x;
    const int w    = tid >> 6;
    const int lane = tid & 63;
    const int m    = lane & 15;
    const int q    = lane >> 4;
    const int row  = 16 * w + m;

    f32x4 acc1[4], acc2[4];
#pragma unroll
    for (int nb = 0; nb < 4; ++nb) { acc1[nb] = fzero(); acc2[nb] = fzero(); }
    float sacc = 0.f;

    const int tile0 = blockIdx.x * GTPB;
    float4 v[GTPB][4];   // all tiles in flight: 16 float4 loads, max MLP
#pragma unroll
    for (int t = 0; t < GTPB; ++t) {
        int tt = tile0 + t;
        const float* src = X + ((size_t)((tt >> 7) * NCH + row)) * L_DIM + ((tt & 127) << 6) + 8 * q;
        v[t][0] = *(const float4*)(src);
        v[t][1] = *(const float4*)(src + 4);
        v[t][2] = *(const float4*)(src + 32);
        v[t][3] = *(const float4*)(src + 36);
    }

#pragma unroll
    for (int t = 0; t < GTPB; ++t) {
        const int p = t & 1;
#pragma unroll
        for (int i = 0; i < 4; ++i) sacc += v[t][i].x + v[t][i].y + v[t][i].z + v[t][i].w;

        bf16x8 Ah[2], Al[2];
#pragma unroll
        for (int k = 0; k < 2; ++k) {
            U8 H, L;
            cvt2(v[t][2 * k].x,     v[t][2 * k].y,     H.u[0], L.u[0]);
            cvt2(v[t][2 * k].z,     v[t][2 * k].w,     H.u[1], L.u[1]);
            cvt2(v[t][2 * k + 1].x, v[t][2 * k + 1].y, H.u[2], L.u[2]);
            cvt2(v[t][2 * k + 1].z, v[t][2 * k + 1].w, H.u[3], L.u[3]);
            Ah[k] = H.v; Al[k] = L.v;
            int chunk = ((w * 2 + k) * 4 + q) * 16 + m;
            *(bf16x8*)&hfrag[p][chunk * 8] = H.v;
            *(bf16x8*)&lfrag[p][chunk * 8] = L.v;
        }
        __syncthreads();

#pragma unroll
        for (int k = 0; k < 2; ++k)
#pragma unroll
            for (int nb = 0; nb < 4; ++nb) {
                int chunk = ((nb * 2 + k) * 4 + q) * 16 + m;
                bf16x8 bh = *(const bf16x8*)&hfrag[p][chunk * 8];
                bf16x8 bl = *(const bf16x8*)&lfrag[p][chunk * 8];
                acc1[nb] = mfma16(Ah[k], bh, acc1[nb]);
                acc2[nb] = mfma16(Ah[k], bl, acc2[nb]);
            }
    }

    // ---- in-block symmetrization: P = G1 + G2 + G2^T ----
    __syncthreads();   // all dbuf reads complete; arena is now free for fg2
#pragma unroll
    for (int nb = 0; nb < 4; ++nb)
#pragma unroll
        for (int r = 0; r < 4; ++r) {
            int grow = 16 * w + 4 * q + r;
            int gcol = 16 * nb + m;
            fg2[grow * 65 + gcol] = acc2[nb][r];
        }
    __syncthreads();

    float* base = P + (size_t)blockIdx.x * PSTRIDE;
#pragma unroll
    for (int nb = 0; nb < 4; ++nb)
#pragma unroll
        for (int r = 0; r < 4; ++r) {
            int grow = 16 * w + 4 * q + r;
            int gcol = 16 * nb + m;
            base[grow * 64 + gcol] = acc1[nb][r] + acc2[nb][r] + fg2[gcol * 65 + grow];
        }
    sacc += __shfl_xor(sacc, 16);
    sacc += __shfl_xor(sacc, 32);
    if (q == 0) base[4096 + row] = sacc;
}

// ---------------- K1b: reduce 1024 partials, 2-way split -> H0 (ws) / H1 (scratch) ----
// 130 blocks: slice s = bid%65 (64 elements), half h = bid/65 (512 partials each).
__global__ __launch_bounds__(256) void reduce_kernel(const float* __restrict__ P,
                                                     float* __restrict__ H0,
                                                     float* __restrict__ H1) {
    const int tid = threadIdx.x;
    const int w = tid >> 6, lane = tid & 63;
    const int s = blockIdx.x % 65;
    const int h = blockIdx.x / 65;
    const int e0 = s * 64;
    const float* base = P + (size_t)(h * 512 + w * 128) * PSTRIDE + e0 + lane;
    float a0 = 0.f, a1 = 0.f, a2 = 0.f, a3 = 0.f;
#pragma unroll 8
    for (int i = 0; i < 32; ++i) {
        const float* p = base + (size_t)(4 * i) * PSTRIDE;
        a0 += p[0];
        a1 += p[PSTRIDE];
        a2 += p[2 * PSTRIDE];
        a3 += p[3 * PSTRIDE];
    }
    float a = (a0 + a1) + (a2 + a3);
    __shared__ float red[4][64];
    red[w][lane] = a;
    __syncthreads();
    if (w == 0) {
        float r = red[0][lane] + red[1][lane] + red[2][lane] + red[3][lane];
        (h ? H1 : H0)[e0 + lane] = r;
    }
}

// ---------------- K2: Newton-Schulz — 512 threads, 8-wave split per matmul -----------
__device__ __forceinline__ void mm_core8(f32x4* acc,
                                         const unsigned short* Xh, const unsigned short* Xl,
                                         const unsigned short* Yh, const unsigned short* Yl,
                                         int rg, int nbb, int m, int q) {
#pragma unroll
    for (int k0 = 0; k0 < 64; k0 += 32) {
        bf16x8 xh = *(const bf16x8*)&Xh[(16 * rg + m) * 72 + k0 + 8 * q];
        bf16x8 xl = *(const bf16x8*)&Xl[(16 * rg + m) * 72 + k0 + 8 * q];
#pragma unroll
        for (int j = 0; j < 2; ++j) {
            int nb = nbb + j;
            bf16x8 yh = *(const bf16x8*)&Yh[(16 * nb + m) * 72 + k0 + 8 * q];
            bf16x8 yl = *(const bf16x8*)&Yl[(16 * nb + m) * 72 + k0 + 8 * q];
            acc[j] = mfma16(xh, yh, acc[j]);
            acc[j] = mfma16(xh, yl, acc[j]);
            acc[j] = mfma16(xl, yh, acc[j]);
        }
    }
}

__device__ __forceinline__ void mm_pl8(unsigned short* Dh, unsigned short* Dl,
                                       const unsigned short* Xh, const unsigned short* Xl,
                                       const unsigned short* Yh, const unsigned short* Yl,
                                       int rg, int nbb, int m, int q) {
    f32x4 acc[2];
    acc[0] = fzero(); acc[1] = fzero();
    mm_core8(acc, Xh, Xl, Yh, Yl, rg, nbb, m, q);
#pragma unroll
    for (int j = 0; j < 2; ++j)
#pragma unroll
        for (int r = 0; r < 4; ++r) {
            int row = 16 * rg + 4 * q + r, col = 16 * (nbb + j) + m;
            unsigned short h, l;
            split16(acc[j][r], h, l);
            Dh[row * 72 + col] = h;
            Dl[row * 72 + col] = l;
        }
}

__global__ __launch_bounds__(512) void ns_kernel(float* __restrict__ ws,
                                                 const float* __restrict__ H1) {
    __shared__ __align__(16) float Pf[64 * 68];
    __shared__ __align__(16) unsigned short Ph[64 * 72], Pl[64 * 72];
    __shared__ __align__(16) unsigned short Sh[64 * 72], Sl[64 * 72];
    __shared__ __align__(16) unsigned short T1h[64 * 72], T1l[64 * 72];
    __shared__ __align__(16) unsigned short T2h[64 * 72], T2l[64 * 72];
    __shared__ float mu[64];
    __shared__ float scal[2];

    const int tid = threadIdx.x;
    const int w8 = tid >> 6, lane = tid & 63;
    const int m = lane & 15, q = lane >> 4;
    const int rg = w8 >> 1, nbb = (w8 & 1) << 1;
    const float inv_m = 1.0f / M_TOT_F;

    if (tid < 64) mu[tid] = (ws[4096 + tid] + H1[4096 + tid]) * inv_m;
    __syncthreads();

    if (tid < 64) {
        int e = tid * 65;   // diagonal (partial already = G1+G2+G2^T)
        float g  = (ws[e] + H1[e]) * inv_m;
        float sd = g - mu[tid] * mu[tid] + EPS_F;
#pragma unroll
        for (int off = 32; off >= 1; off >>= 1) sd += __shfl_xor(sd, off);
        if (tid == 0) { scal[0] = 1.0f / sd; scal[1] = sqrtf(1.0f / sd); }
    }
    __syncthreads();
    const float rTr = scal[0];

    // S_N planes + closed-form NS iter 1: P1 = 1.5 I - 0.5 S_N
    for (int e = tid; e < 4096; e += 512) {
        int i = e >> 6, j = e & 63;
        float g   = (ws[e] + H1[e]) * inv_m;
        float sig = g - mu[i] * mu[j] + ((i == j) ? EPS_F : 0.f);
        float sn  = sig * rTr;
        unsigned short h, l;
        split16(sn, h, l);
        Sh[i * 72 + j] = h; Sl[i * 72 + j] = l;
        float pv = ((i == j) ? 1.5f : 0.f) - 0.5f * sn;
        Pf[i * 68 + j] = pv;
        split16(pv, h, l);
        Ph[i * 72 + j] = h; Pl[i * 72 + j] = l;
    }
    __syncthreads();

    for (int it = 0; it < 4; ++it) {
        mm_pl8(T1h, T1l, Ph, Pl, Ph, Pl, rg, nbb, m, q);   // T1 = P^2
        __syncthreads();
        mm_pl8(T2h, T2l, T1h, T1l, Ph, Pl, rg, nbb, m, q); // T2 = P^3
        __syncthreads();
        f32x4 acc[2];                                       // U = P^3 * S_N
        acc[0] = fzero(); acc[1] = fzero();
        mm_core8(acc, T2h, T2l, Sh, Sl, rg, nbb, m, q);
#pragma unroll
        for (int j = 0; j < 2; ++j)
#pragma unroll
            for (int r = 0; r < 4; ++r) {
                int row = 16 * rg + 4 * q + r, col = 16 * (nbb + j) + m;
                int idx = row * 68 + col;
                float pv = 1.5f * Pf[idx] - 0.5f * acc[j][r];
                Pf[idx] = pv;
                unsigned short h, l;
                split16(pv, h, l);
                Ph[row * 72 + col] = h;
                Pl[row * 72 + col] = l;
            }
        __syncthreads();
    }

    const float s = scal[1];
    unsigned short* hp = (unsigned short*)ws;
    unsigned short* lp = hp + 4096;
    for (int e = tid; e < 4096; e += 512) {
        int i = e >> 6, j = e & 63;
        float v = Pf[i * 68 + j] * s;
        unsigned short h, l;
        split16(v, h, l);
        hp[e] = h;
        lp[e] = l;
    }
    if (tid < 64) {
        float a = 0.f;
#pragma unroll 8
        for (int k = 0; k < 64; ++k) a += Pf[tid * 68 + k] * mu[k];
        ws[8256 + tid] = -a * s;
    }
}

// ---------------- K3: Y = wm @ x + bias — all 4 tiles' loads issued upfront ----------
__global__ __launch_bounds__(256) void apply_kernel(const float* __restrict__ X,
                                                    float* __restrict__ Y,
                                                    const float* __restrict__ ws) {
    __shared__ __align__(16) unsigned short hplane[2][4096];
    __shared__ __align__(16) unsigned short lplane[2][4096];
    const int tid  = threadIdx.x;
    const int w    = tid >> 6;
    const int lane = tid & 63;
    const int m    = lane & 15;
    const int q    = lane >> 4;
    const int cp   = tid & 31;      // channel pair rows 2cp, 2cp+1
    const int lg   = tid >> 5;      // 0..7

    const unsigned short* hp = (const unsigned short*)ws;
    const unsigned short* lp = hp + 4096;
    bf16x8 Ah[2], Al[2];
#pragma unroll
    for (int kk = 0; kk < 2; ++kk) {
        Ah[kk] = *(const bf16x8*)&hp[(16 * w + m) * 64 + 32 * kk + 8 * q];
        Al[kk] = *(const bf16x8*)&lp[(16 * w + m) * 64 + 32 * kk + 8 * q];
    }
    const float4 bias4 = *(const float4*)&ws[8256 + 16 * w + 4 * q];

    float4 va[ATPB][2], vb[ATPB][2];   // all tiles in flight: 16 float4 loads
#pragma unroll
    for (int t = 0; t < ATPB; ++t) {
        int tile = blockIdx.x * ATPB + t;
        const float* xb = X + (size_t)(tile >> 7) * (NCH * L_DIM) + ((tile & 127) << 6)
                          + (size_t)(2 * cp) * L_DIM + 4 * lg;
#pragma unroll
        for (int ss = 0; ss < 2; ++ss) {
            va[t][ss] = *(const float4*)(xb + 32 * ss);
            vb[t][ss] = *(const float4*)(xb + 32 * ss + L_DIM);
        }
    }

#pragma unroll
    for (int t = 0; t < ATPB; ++t) {
        int tile = blockIdx.x * ATPB + t;
        int bidx = tile >> 7;
        int l0   = (tile & 127) << 6;
        const int p = t & 1;
        unsigned* hw2 = (unsigned*)hplane[p];
        unsigned* lw2 = (unsigned*)lplane[p];

#pragma unroll
        for (int ss = 0; ss < 2; ++ss) {
            float fa[4], fb[4];
            *(float4*)fa = va[t][ss];
            *(float4*)fb = vb[t][ss];
#pragma unroll
            for (int i = 0; i < 4; ++i) {
                int l = 4 * lg + 32 * ss + i;
                unsigned h, lo2;
                cvt2(fa[i], fb[i], h, lo2);
                int widx = l * 32 + (((cp >> 2) ^ (l & 7)) << 2) + (cp & 3);
                hw2[widx] = h;
                lw2[widx] = lo2;
            }
        }
        __syncthreads();

        f32x4 acc[4];
#pragma unroll
        for (int nb = 0; nb < 4; ++nb) {
            acc[nb][0] = bias4.x; acc[nb][1] = bias4.y;
            acc[nb][2] = bias4.z; acc[nb][3] = bias4.w;
        }
#pragma unroll
        for (int kk = 0; kk < 2; ++kk)
#pragma unroll
            for (int nb = 0; nb < 4; ++nb) {
                int l = 16 * nb + m;
                int saddr = l * 64 + ((((4 * kk + q) ^ (l & 7))) << 3);
                bf16x8 bh = *(const bf16x8*)&hplane[p][saddr];
                bf16x8 bl = *(const bf16x8*)&lplane[p][saddr];
                acc[nb] = mfma16(Ah[kk], bh, acc[nb]);
                acc[nb] = mfma16(Ah[kk], bl, acc[nb]);
                acc[nb] = mfma16(Al[kk], bh, acc[nb]);
            }

#pragma unroll
        for (int nb = 0; nb < 4; ++nb)
#pragma unroll
            for (int rr = 0; rr < 4; ++rr)
                Y[((size_t)bidx * NCH + 16 * w + 4 * q + rr) * L_DIM + l0 + 16 * nb + m] = acc[nb][rr];
    }
}

extern "C" void kernel_launch(void* const* d_in, const int* in_sizes, int n_in,
                              void* d_out, int out_size, void* d_ws, size_t ws_size,
                              hipStream_t stream) {
    const float* X = (const float*)d_in[0];
    float* Y  = (float*)d_out;
    float* ws = (float*)d_ws;
    float* scratch = (float*)d_out;                       // partials live in d_out pre-apply
    float* H1 = scratch + (size_t)1024 * PSTRIDE;         // second half-sum, also in d_out

    hipLaunchKernelGGL(gram_kernel,   dim3(1024), dim3(256), 0, stream, X, scratch);
    hipLaunchKernelGGL(reduce_kernel, dim3(130),  dim3(256), 0, stream, scratch, ws, H1);
    hipLaunchKernelGGL(ns_kernel,     dim3(1),    dim3(512), 0, stream, ws, H1);
    hipLaunchKernelGGL(apply_kernel,  dim3(1024), dim3(256), 0, stream, X, Y, ws);
}